// Round 1
// baseline (1158.156 us; speedup 1.0000x reference)
//
#include <hip/hip_runtime.h>
#include <stdint.h>

#define NP    676
#define NPAD  768
#define DD    384
#define MM    200000
#define IMG   224

typedef unsigned int u32;
typedef unsigned long long u64;
typedef short bf16x8 __attribute__((ext_vector_type(8)));
typedef float f32x4 __attribute__((ext_vector_type(4)));

// ---- workspace layout (bytes) ----
#define WS_PACKED   0u         // u64[768]   max-dot flipped keys per row
#define WS_SCAL     6144u      // u32 s_idx, u32 j_star, f32 s_star
#define WS_MV       6400u      // f32[768]   min_val per row
#define WS_TOPS     9728u      // u64[128*5] per-block top5 of d_star
#define WS_PNORM    15360u     // f32[768*384] normalized patch
#define WS_PNB      1195008u   // ushort[768*384] bf16 normalized patch
#define WS_DSTAR    1784832u   // u64[200000] packed (dist,idx)
#define WS_BUFA     3384832u   // f32[50176] resized map
#define WS_BUFB     3585536u   // f32[50176] h-blurred map

__device__ inline unsigned short f2bf(float f) {
  u32 u = __float_as_uint(f);
  u += 0x7FFFu + ((u >> 16) & 1u);
  return (unsigned short)(u >> 16);
}
// monotonic u32 key for float (ascending float -> ascending key)
__device__ inline u32 flipf(float f) {
  u32 u = __float_as_uint(f);
  return u ^ ((u32)((int)u >> 31) | 0x80000000u);
}
__device__ inline float unflipf(u32 k) {
  u32 u = (k & 0x80000000u) ? (k ^ 0x80000000u) : ~k;
  return __uint_as_float(u);
}
__device__ inline u64 shfl_xor_u64(u64 v, int m) {
  union { u64 v; int i[2]; } u;
  u.v = v;
  u.i[0] = __shfl_xor(u.i[0], m, 64);
  u.i[1] = __shfl_xor(u.i[1], m, 64);
  return u.v;
}

// ---- K0: init packed keys to 0 (all real keys > 0) ----
__global__ void k_init(u64* __restrict__ packed_) {
  int i = blockIdx.x * 256 + threadIdx.x;
  if (i < NPAD) packed_[i] = 0ull;
}

// ---- K1: L2-normalize patch rows, write fp32 + bf16, pad rows to 768 ----
__global__ void k_norm(const float* __restrict__ patch, float* __restrict__ pnorm,
                       unsigned short* __restrict__ pnb) {
  __shared__ float red[2];
  __shared__ float scs;
  int i = blockIdx.x, t = threadIdx.x;
  if (i >= NP) {
    for (int j = 0; j < 3; ++j) {
      pnorm[(size_t)i * DD + t + 128 * j] = 0.f;
      pnb[(size_t)i * DD + t + 128 * j] = 0;
    }
    return;
  }
  float x0 = patch[(size_t)i * DD + t];
  float x1 = patch[(size_t)i * DD + t + 128];
  float x2 = patch[(size_t)i * DD + t + 256];
  float s = x0 * x0 + x1 * x1 + x2 * x2;
#pragma unroll
  for (int m = 1; m < 64; m <<= 1) s += __shfl_xor(s, m, 64);
  if ((t & 63) == 0) red[t >> 6] = s;
  __syncthreads();
  if (t == 0) scs = 1.f / fmaxf(sqrtf(red[0] + red[1]), 1e-12f);
  __syncthreads();
  float k = scs;
  pnorm[(size_t)i * DD + t]       = x0 * k;
  pnorm[(size_t)i * DD + t + 128] = x1 * k;
  pnorm[(size_t)i * DD + t + 256] = x2 * k;
  pnb[(size_t)i * DD + t]       = f2bf(x0 * k);
  pnb[(size_t)i * DD + t + 128] = f2bf(x1 * k);
  pnb[(size_t)i * DD + t + 256] = f2bf(x2 * k);
}

// ---- K2: main pass. WG = 256 lib cols, chunks of 64 in LDS; 6 row-tiles of 128.
// 16x16x32 bf16 MFMA; A-frags direct from global (L2-hot patch), B from LDS.
// Row reduction in max-dot key space (dist = sqrt(2-2*dot) is monotone-decreasing).
__global__ __launch_bounds__(256, 2) void k_pass1(const unsigned short* __restrict__ pnb,
                                                  const float* __restrict__ lib,
                                                  u64* __restrict__ packed_) {
  __shared__ __align__(16) unsigned short bt[64 * 392];  // 64 cols x 384 k, stride 392
  __shared__ u64 smax[NPAD];
  const int t = threadIdx.x;
  const int col0 = blockIdx.x * 256;
  for (int i = t; i < NPAD; i += 256) smax[i] = 0ull;
  const int wave = t >> 6, lane = t & 63;
  const int rowhalf = wave >> 1, colhalf = wave & 1;
  const int quad = lane >> 4, l15 = lane & 15;

  for (int cc = 0; cc < 4; ++cc) {
    __syncthreads();  // previous chunk compute done (and smax init at cc=0)
    {  // stage 64-col chunk: fp32 -> bf16 into LDS
      const int cbase = col0 + cc * 64;
      int vc = MM - cbase;
      vc = vc < 0 ? 0 : (vc > 64 ? 64 : vc);
      const int v4 = vc * 96;
      const float4* src = (const float4*)lib + (size_t)cbase * 96;
      for (int it = 0; it < 24; ++it) {
        int idx = it * 256 + t;        // < 6144
        int c = idx / 96, k4 = idx - c * 96;
        ushort4 w;
        if (idx < v4) {
          float4 f = src[idx];
          w.x = f2bf(f.x); w.y = f2bf(f.y); w.z = f2bf(f.z); w.w = f2bf(f.w);
        } else {
          w.x = 0; w.y = 0; w.z = 0; w.w = 0;
        }
        *(ushort4*)&bt[c * 392 + k4 * 4] = w;
      }
    }
    __syncthreads();
    for (int rt = 0; rt < 6; ++rt) {
      const int rowbase = rt * 128 + rowhalf * 64;
      f32x4 acc[4][2];
#pragma unroll
      for (int mi = 0; mi < 4; ++mi)
#pragma unroll
        for (int ni = 0; ni < 2; ++ni) {
          acc[mi][ni][0] = 0.f; acc[mi][ni][1] = 0.f;
          acc[mi][ni][2] = 0.f; acc[mi][ni][3] = 0.f;
        }
      const unsigned short* ap = pnb + (size_t)(rowbase + l15) * DD + quad * 8;
      const unsigned short* bp = &bt[(colhalf * 32 + l15) * 392 + quad * 8];
#pragma unroll
      for (int kt = 0; kt < 12; ++kt) {
        bf16x8 a[4], b[2];
#pragma unroll
        for (int mi = 0; mi < 4; ++mi)
          a[mi] = *(const bf16x8*)(ap + mi * 16 * DD + kt * 32);
#pragma unroll
        for (int ni = 0; ni < 2; ++ni)
          b[ni] = *(const bf16x8*)(bp + ni * 16 * 392 + kt * 32);
#pragma unroll
        for (int mi = 0; mi < 4; ++mi)
#pragma unroll
          for (int ni = 0; ni < 2; ++ni)
            acc[mi][ni] = __builtin_amdgcn_mfma_f32_16x16x32_bf16(a[mi], b[ni], acc[mi][ni], 0, 0, 0);
      }
      // epilogue: per-row max-dot (=> min dist), tie -> smaller lib idx
      const int nbase = col0 + cc * 64 + colhalf * 32 + l15;
#pragma unroll
      for (int mi = 0; mi < 4; ++mi) {
#pragma unroll
        for (int r = 0; r < 4; ++r) {
          u64 v0 = ((u64)flipf(acc[mi][0][r]) << 32) | (u32)(0xFFFFFFFFu - (u32)nbase);
          u64 v1 = ((u64)flipf(acc[mi][1][r]) << 32) | (u32)(0xFFFFFFFFu - (u32)(nbase + 16));
          u64 v = v0 > v1 ? v0 : v1;
#pragma unroll
          for (int m = 1; m < 16; m <<= 1) {
            u64 o = shfl_xor_u64(v, m);
            v = o > v ? o : v;
          }
          if (l15 == 0) atomicMax(&smax[rowbase + mi * 16 + quad * 4 + r], v);
        }
      }
    }
  }
  __syncthreads();
  for (int i = t; i < NPAD; i += 256) atomicMax(&packed_[i], smax[i]);
}

// ---- K3: min_val[i], s_idx = argmax(min_val) (first-index tie), j_star ----
__global__ void k_select(const u64* __restrict__ packed_, u32* __restrict__ scal,
                         float* __restrict__ mv) {
  __shared__ u64 red[256];
  int t = threadIdx.x;
  u64 best = 0ull;
  for (int i = t; i < NP; i += 256) {
    u64 p = packed_[i];
    float d = unflipf((u32)(p >> 32));
    float dist = sqrtf(fmaxf(2.f - 2.f * d, 0.f));
    mv[i] = dist;
    u64 key = ((u64)__float_as_uint(dist) << 32) | (u32)(0xFFFFFFFFu - (u32)i);
    if (key > best) best = key;
  }
  red[t] = best;
  __syncthreads();
  for (int s = 128; s > 0; s >>= 1) {
    if (t < s && red[t + s] > red[t]) red[t] = red[t + s];
    __syncthreads();
  }
  if (t == 0) {
    u64 k = red[0];
    u32 sidx = 0xFFFFFFFFu - (u32)k;
    u64 p = packed_[sidx];
    u32 jstar = 0xFFFFFFFFu - (u32)p;
    scal[0] = sidx;
    scal[1] = jstar;
    ((float*)scal)[2] = __uint_as_float((u32)(k >> 32));
  }
}

// ---- K4: d_star = dist(m_star, lib[j]) for all j; packed (distbits<<32)|j ----
__global__ void k_dstar(const float* __restrict__ lib, const u32* __restrict__ scal,
                        u64* __restrict__ dstar) {
  int gid = blockIdx.x * 256 + threadIdx.x;
  int wid = gid >> 6, lane = gid & 63;
  u32 jstar = scal[1];
  const float* ms = lib + (size_t)jstar * DD;
  float m[6];
#pragma unroll
  for (int r = 0; r < 6; ++r) m[r] = ms[lane + 64 * r];
  for (int row = wid; row < MM; row += 3200) {
    const float* xr = lib + (size_t)row * DD;
    float dot = 0.f;
#pragma unroll
    for (int r = 0; r < 6; ++r) dot += m[r] * xr[lane + 64 * r];
#pragma unroll
    for (int mm = 1; mm < 64; mm <<= 1) dot += __shfl_xor(dot, mm, 64);
    if (lane == 0) {
      float dist = sqrtf(fmaxf(2.f - 2.f * dot, 0.f));
      dstar[row] = ((u64)__float_as_uint(dist) << 32) | (u32)row;
    }
  }
}

__device__ inline void merge5(const u64* a, const u64* b, u64* o) {
  int ia = 0, ib = 0;
#pragma unroll
  for (int j = 0; j < 5; ++j) {
    u64 va = a[ia], vb = b[ib];
    if (va <= vb) { o[j] = va; ++ia; } else { o[j] = vb; ++ib; }
  }
}

// ---- K5a: per-block top-5 smallest of d_star ----
__global__ void k_top5a(const u64* __restrict__ dstar, u64* __restrict__ tops) {
  __shared__ u64 l[256 * 5];
  int t = threadIdx.x, b = blockIdx.x;
  int start = b * 1563;
  int end = start + 1563; if (end > MM) end = MM;
  u64 a0 = ~0ull, a1 = ~0ull, a2 = ~0ull, a3 = ~0ull, a4 = ~0ull;
  for (int i = start + t; i < end; i += 256) {
    u64 v = dstar[i];
    if (v < a4) {
      if (v < a0)      { a4 = a3; a3 = a2; a2 = a1; a1 = a0; a0 = v; }
      else if (v < a1) { a4 = a3; a3 = a2; a2 = a1; a1 = v; }
      else if (v < a2) { a4 = a3; a3 = a2; a2 = v; }
      else if (v < a3) { a4 = a3; a3 = v; }
      else             { a4 = v; }
    }
  }
  l[t * 5 + 0] = a0; l[t * 5 + 1] = a1; l[t * 5 + 2] = a2; l[t * 5 + 3] = a3; l[t * 5 + 4] = a4;
  __syncthreads();
  for (int s = 128; s > 0; s >>= 1) {
    if (t < s) {
      u64 o[5];
      merge5(&l[t * 5], &l[(t + s) * 5], o);
#pragma unroll
      for (int j = 0; j < 5; ++j) l[t * 5 + j] = o[j];
    }
    __syncthreads();
  }
  if (t < 5) tops[b * 5 + t] = l[t];
}

// ---- K5b: global top-5 merge + final scalar s ----
__global__ void k_final(const u64* __restrict__ tops, const u32* __restrict__ scal,
                        const float* __restrict__ pnorm, const float* __restrict__ lib,
                        float* __restrict__ out) {
  __shared__ u64 l[128 * 5];
  __shared__ u32 nn[5];
  int t = threadIdx.x;
  if (t < 128) {
#pragma unroll
    for (int j = 0; j < 5; ++j) l[t * 5 + j] = tops[t * 5 + j];
  }
  __syncthreads();
  for (int s = 64; s > 0; s >>= 1) {
    if (t < s) {
      u64 o[5];
      merge5(&l[t * 5], &l[(t + s) * 5], o);
#pragma unroll
      for (int j = 0; j < 5; ++j) l[t * 5 + j] = o[j];
    }
    __syncthreads();
  }
  if (t < 5) nn[t] = (u32)l[t];
  __syncthreads();
  if (t < 64) {
    int lane = t;
    u32 sidx = scal[0], jstar = scal[1];
    const float* mt = pnorm + (size_t)sidx * DD;
    float mtv[6];
#pragma unroll
    for (int r = 0; r < 6; ++r) mtv[r] = mt[lane + 64 * r];
    float dist[6];
    for (int n = 0; n < 6; ++n) {
      u32 idx = (n == 0) ? jstar : nn[n - 1];
      const float* v = lib + (size_t)idx * DD;
      float p = 0.f;
#pragma unroll
      for (int r = 0; r < 6; ++r) {
        float d = mtv[r] - v[lane + 64 * r];
        p += d * d;
      }
#pragma unroll
      for (int m = 1; m < 64; m <<= 1) p += __shfl_xor(p, m, 64);
      dist[n] = sqrtf(p);
    }
    if (lane == 0) {
      float nrm = dist[0];  // ||m_test_star - m_star|| == s_star (fp32)
      float den = 0.f;
      for (int n = 1; n < 6; ++n) den += expf(dist[n]);
      out[0] = (1.f - expf(nrm) / den) * nrm;
    }
  }
}

// ---- K6: bilinear resize 26x26 -> 224x224 (half-pixel, clamped) ----
__global__ void k_resize(const float* __restrict__ mv, float* __restrict__ A) {
  int i = blockIdx.x * 256 + threadIdx.x;
  int Y = i / IMG, X = i - Y * IMG;
  const float sc = 26.f / 224.f;
  float sy = (Y + 0.5f) * sc - 0.5f;
  float sx = (X + 0.5f) * sc - 0.5f;
  float fy = sy - floorf(sy), fx = sx - floorf(sx);
  int y0 = (int)floorf(sy), x0 = (int)floorf(sx);
  int y1 = y0 + 1, x1 = x0 + 1;
  y0 = min(max(y0, 0), 25); y1 = min(max(y1, 0), 25);
  x0 = min(max(x0, 0), 25); x1 = min(max(x1, 0), 25);
  float v00 = mv[y0 * 26 + x0], v01 = mv[y0 * 26 + x1];
  float v10 = mv[y1 * 26 + x0], v11 = mv[y1 * 26 + x1];
  A[i] = (1.f - fy) * ((1.f - fx) * v00 + fx * v01) + fy * ((1.f - fx) * v10 + fx * v11);
}

// ---- K7/K8: separable 33-tap Gaussian (sigma=4), reflect padding ----
__global__ void k_blurh(const float* __restrict__ A, float* __restrict__ B) {
  __shared__ float kw[33];
  __shared__ float kinv;
  int t = threadIdx.x;
  if (t < 33) {
    float x = ((float)t - 16.f) * 0.25f;
    kw[t] = expf(-0.5f * x * x);
  }
  __syncthreads();
  if (t == 0) {
    float s = 0.f;
    for (int j = 0; j < 33; ++j) s += kw[j];
    kinv = 1.f / s;
  }
  __syncthreads();
  int i = blockIdx.x * 256 + t;
  int Y = i / IMG, X = i - Y * IMG;
  float s = 0.f;
  for (int j = 0; j < 33; ++j) {
    int xx = X + j - 16;
    xx = xx < 0 ? -xx : (xx > 223 ? 446 - xx : xx);
    s += kw[j] * A[Y * IMG + xx];
  }
  B[i] = s * kinv;
}

__global__ void k_blurv(const float* __restrict__ B, float* __restrict__ out) {
  __shared__ float kw[33];
  __shared__ float kinv;
  int t = threadIdx.x;
  if (t < 33) {
    float x = ((float)t - 16.f) * 0.25f;
    kw[t] = expf(-0.5f * x * x);
  }
  __syncthreads();
  if (t == 0) {
    float s = 0.f;
    for (int j = 0; j < 33; ++j) s += kw[j];
    kinv = 1.f / s;
  }
  __syncthreads();
  int i = blockIdx.x * 256 + t;
  int Y = i / IMG, X = i - Y * IMG;
  float s = 0.f;
  for (int j = 0; j < 33; ++j) {
    int yy = Y + j - 16;
    yy = yy < 0 ? -yy : (yy > 223 ? 446 - yy : yy);
    s += kw[j] * B[yy * IMG + X];
  }
  out[1 + i] = s * kinv;  // out[0] = s scalar, map follows
}

extern "C" void kernel_launch(void* const* d_in, const int* in_sizes, int n_in,
                              void* d_out, int out_size, void* d_ws, size_t ws_size,
                              hipStream_t stream) {
  const float* patch = (const float*)d_in[0];   // [676, 384]
  const float* lib   = (const float*)d_in[1];   // [200000, 384]
  float* out = (float*)d_out;                   // [1 + 224*224]
  char* w = (char*)d_ws;

  u64*  packed_ = (u64*)(w + WS_PACKED);
  u32*  scal    = (u32*)(w + WS_SCAL);
  float* mv     = (float*)(w + WS_MV);
  u64*  tops    = (u64*)(w + WS_TOPS);
  float* pnorm  = (float*)(w + WS_PNORM);
  unsigned short* pnb = (unsigned short*)(w + WS_PNB);
  u64*  dstar   = (u64*)(w + WS_DSTAR);
  float* bufA   = (float*)(w + WS_BUFA);
  float* bufB   = (float*)(w + WS_BUFB);

  k_init  <<<3,   256, 0, stream>>>(packed_);
  k_norm  <<<NPAD,128, 0, stream>>>(patch, pnorm, pnb);
  k_pass1 <<<782, 256, 0, stream>>>(pnb, lib, packed_);
  k_select<<<1,   256, 0, stream>>>(packed_, scal, mv);
  k_dstar <<<800, 256, 0, stream>>>(lib, scal, dstar);
  k_top5a <<<128, 256, 0, stream>>>(dstar, tops);
  k_final <<<1,   256, 0, stream>>>(tops, scal, pnorm, lib, out);
  k_resize<<<196, 256, 0, stream>>>(mv, bufA);
  k_blurh <<<196, 256, 0, stream>>>(bufA, bufB);
  k_blurv <<<196, 256, 0, stream>>>(bufB, out);
}

// Round 2
// 1094.819 us; speedup vs baseline: 1.0579x; 1.0579x over previous
//
#include <hip/hip_runtime.h>
#include <stdint.h>

#define NP    676
#define NPAD  768
#define DD    384
#define MM    200000
#define IMG   224

typedef unsigned int u32;
typedef unsigned long long u64;
typedef short bf16x8 __attribute__((ext_vector_type(8)));
typedef float f32x4 __attribute__((ext_vector_type(4)));

// ---- workspace layout (bytes) ----
#define WS_PACKED   0u         // u64[768]   max-dot keys per row
#define WS_SCAL     6144u      // u32 s_idx, u32 j_star, f32 s_star
#define WS_MV       6400u      // f32[768]   min_val per row
#define WS_TOPS     9728u      // u64[128*5] per-block top5 of d_star
#define WS_PNORM    15360u     // f32[768*384] normalized patch
#define WS_PNB      1195008u   // ushort[768*384] bf16 normalized patch
#define WS_DSTAR    1784832u   // u64[200000] packed (dist,idx)
#define WS_BUFA     3384832u   // f32[50176] resized map
#define WS_BUFB     3585536u   // f32[50176] h-blurred map

__device__ inline unsigned short f2bf(float f) {
  u32 u = __float_as_uint(f);
  u += 0x7FFFu + ((u >> 16) & 1u);
  return (unsigned short)(u >> 16);
}
// monotonic u32 key for float (ascending float -> ascending key)
__device__ inline u32 flipf(float f) {
  u32 u = __float_as_uint(f);
  return u ^ ((u32)((int)u >> 31) | 0x80000000u);
}
__device__ inline float unflipf(u32 k) {
  u32 u = (k & 0x80000000u) ? (k ^ 0x80000000u) : ~k;
  return __uint_as_float(u);
}

// ---- K0: init packed keys to 0 (all real keys > 0) ----
__global__ void k_init(u64* __restrict__ packed_) {
  int i = blockIdx.x * 256 + threadIdx.x;
  if (i < NPAD) packed_[i] = 0ull;
}

// ---- K1: L2-normalize patch rows, write fp32 + bf16, pad rows to 768 ----
__global__ void k_norm(const float* __restrict__ patch, float* __restrict__ pnorm,
                       unsigned short* __restrict__ pnb) {
  __shared__ float red[2];
  __shared__ float scs;
  int i = blockIdx.x, t = threadIdx.x;
  if (i >= NP) {
    for (int j = 0; j < 3; ++j) {
      pnorm[(size_t)i * DD + t + 128 * j] = 0.f;
      pnb[(size_t)i * DD + t + 128 * j] = 0;
    }
    return;
  }
  float x0 = patch[(size_t)i * DD + t];
  float x1 = patch[(size_t)i * DD + t + 128];
  float x2 = patch[(size_t)i * DD + t + 256];
  float s = x0 * x0 + x1 * x1 + x2 * x2;
#pragma unroll
  for (int m = 1; m < 64; m <<= 1) s += __shfl_xor(s, m, 64);
  if ((t & 63) == 0) red[t >> 6] = s;
  __syncthreads();
  if (t == 0) scs = 1.f / fmaxf(sqrtf(red[0] + red[1]), 1e-12f);
  __syncthreads();
  float k = scs;
  pnorm[(size_t)i * DD + t]       = x0 * k;
  pnorm[(size_t)i * DD + t + 128] = x1 * k;
  pnorm[(size_t)i * DD + t + 256] = x2 * k;
  pnb[(size_t)i * DD + t]       = f2bf(x0 * k);
  pnb[(size_t)i * DD + t + 128] = f2bf(x1 * k);
  pnb[(size_t)i * DD + t + 256] = f2bf(x2 * k);
}

// ---- K2: main pass. WG = 256 lib cols; B staged per 64-col chunk, A staged
// per 128-row tile, both in LDS (stride 392 shorts = 2-way bank alias, free).
// Per-thread running max in registers as packed u32 keys; single epilogue.
__global__ __launch_bounds__(256, 1) void k_pass1(const unsigned short* __restrict__ pnb,
                                                  const float* __restrict__ lib,
                                                  u64* __restrict__ packed_) {
  __shared__ __align__(16) unsigned short at[128 * 392];  // 98 KB
  __shared__ __align__(16) unsigned short bt[64 * 392];   // 49 KB
  __shared__ u64 smax[NPAD];                              // 6 KB
  const int t = threadIdx.x;
  const int col0 = blockIdx.x * 256;
  const int wave = t >> 6, lane = t & 63;
  const int rowhalf = wave >> 1, colhalf = wave & 1;
  const int quad = lane >> 4, l15 = lane & 15;

  u32 best[6][16];
#pragma unroll
  for (int rt = 0; rt < 6; ++rt)
#pragma unroll
    for (int j = 0; j < 16; ++j) best[rt][j] = 0u;

#pragma unroll 1
  for (int cc = 0; cc < 4; ++cc) {
    const int cbase = col0 + cc * 64;
    if (cbase >= MM) break;            // last WG: only chunk 0 is valid (exactly)
    __syncthreads();                   // prior compute done reading bt
    {  // stage B: 64 cols fp32 -> bf16
      const float4* src = (const float4*)lib + (size_t)cbase * 96;
#pragma unroll 1
      for (int it = 0; it < 24; ++it) {
        int idx = it * 256 + t;        // < 6144, 16B of fp32 -> 8B of bf16
        int c = idx / 96, k4 = idx - c * 96;
        float4 f = src[idx];
        ushort4 w;
        w.x = f2bf(f.x); w.y = f2bf(f.y); w.z = f2bf(f.z); w.w = f2bf(f.w);
        *(ushort4*)&bt[c * 392 + k4 * 4] = w;
      }
    }
    const u32 ccb = ((u32)cc << 5) | (u32)l15;
#pragma unroll
    for (int rt = 0; rt < 6; ++rt) {
      __syncthreads();                 // prior compute done reading at (and bt staged)
      {  // stage A: rows rt*128 .. +128, bf16 copy 16B/thread/iter
        const uint4* src = (const uint4*)(pnb + (size_t)rt * 128 * DD);
#pragma unroll 1
        for (int it = 0; it < 24; ++it) {
          int idx = it * 256 + t;      // < 6144
          int r = idx / 48, k8 = idx - r * 48;
          *(uint4*)&at[r * 392 + k8 * 8] = src[idx];
        }
      }
      __syncthreads();
      f32x4 acc[4][2];
#pragma unroll
      for (int mi = 0; mi < 4; ++mi)
#pragma unroll
        for (int ni = 0; ni < 2; ++ni) {
          acc[mi][ni][0] = 0.f; acc[mi][ni][1] = 0.f;
          acc[mi][ni][2] = 0.f; acc[mi][ni][3] = 0.f;
        }
      const unsigned short* ap = &at[(rowhalf * 64 + l15) * 392 + quad * 8];
      const unsigned short* bp = &bt[(colhalf * 32 + l15) * 392 + quad * 8];
#pragma unroll
      for (int kt = 0; kt < 12; ++kt) {
        bf16x8 a[4], b[2];
#pragma unroll
        for (int mi = 0; mi < 4; ++mi)
          a[mi] = *(const bf16x8*)(ap + mi * (16 * 392) + kt * 32);
#pragma unroll
        for (int ni = 0; ni < 2; ++ni)
          b[ni] = *(const bf16x8*)(bp + ni * (16 * 392) + kt * 32);
#pragma unroll
        for (int mi = 0; mi < 4; ++mi)
#pragma unroll
          for (int ni = 0; ni < 2; ++ni)
            acc[mi][ni] = __builtin_amdgcn_mfma_f32_16x16x32_bf16(a[mi], b[ni], acc[mi][ni], 0, 0, 0);
      }
      // fold into per-thread running best (packed key: dot[31:7] | cc<<5 | sel<<4 | l15)
#pragma unroll
      for (int mi = 0; mi < 4; ++mi)
#pragma unroll
        for (int r = 0; r < 4; ++r) {
          u32 k0 = (flipf(acc[mi][0][r]) & 0xFFFFFF80u) | ccb;
          u32 k1 = (flipf(acc[mi][1][r]) & 0xFFFFFF80u) | ccb | 16u;
          u32 kk = k0 > k1 ? k0 : k1;
          if (kk > best[rt][mi * 4 + r]) best[rt][mi * 4 + r] = kk;
        }
    }
  }

  // ---- single epilogue: butterfly over 16 lanes, then LDS/global merge ----
  for (int i = t; i < NPAD; i += 256) smax[i] = 0ull;
  __syncthreads();
#pragma unroll
  for (int rt = 0; rt < 6; ++rt) {
    const int rowbase = rt * 128 + rowhalf * 64;
#pragma unroll
    for (int mi = 0; mi < 4; ++mi)
#pragma unroll
      for (int r = 0; r < 4; ++r) {
        u32 k = best[rt][mi * 4 + r];
#pragma unroll
        for (int m = 1; m < 16; m <<= 1) {
          u32 o = (u32)__shfl_xor((int)k, m, 64);
          k = o > k ? o : k;
        }
        if (l15 == 0) {
          int col = col0 + (int)((k >> 5) & 3u) * 64 + colhalf * 32 + (int)(k & 31u);
          u64 g = ((u64)(k & 0xFFFFFF80u) << 32) | (u64)(0xFFFFFFFFu - (u32)col);
          atomicMax(&smax[rowbase + mi * 16 + quad * 4 + r], g);
        }
      }
  }
  __syncthreads();
  for (int i = t; i < NPAD; i += 256) atomicMax(&packed_[i], smax[i]);
}

// ---- K3: min_val[i], s_idx = argmax(min_val) (first-index tie), j_star ----
__global__ void k_select(const u64* __restrict__ packed_, u32* __restrict__ scal,
                         float* __restrict__ mv) {
  __shared__ u64 red[256];
  int t = threadIdx.x;
  u64 best = 0ull;
  for (int i = t; i < NP; i += 256) {
    u64 p = packed_[i];
    float d = unflipf((u32)(p >> 32));
    float dist = sqrtf(fmaxf(2.f - 2.f * d, 0.f));
    mv[i] = dist;
    u64 key = ((u64)__float_as_uint(dist) << 32) | (u32)(0xFFFFFFFFu - (u32)i);
    if (key > best) best = key;
  }
  red[t] = best;
  __syncthreads();
  for (int s = 128; s > 0; s >>= 1) {
    if (t < s && red[t + s] > red[t]) red[t] = red[t + s];
    __syncthreads();
  }
  if (t == 0) {
    u64 k = red[0];
    u32 sidx = 0xFFFFFFFFu - (u32)k;
    u64 p = packed_[sidx];
    u32 jstar = 0xFFFFFFFFu - (u32)p;
    scal[0] = sidx;
    scal[1] = jstar;
    ((float*)scal)[2] = __uint_as_float((u32)(k >> 32));
  }
}

// ---- K4: d_star = dist(m_star, lib[j]); 4 rows per wave via 16-lane groups ----
__global__ void k_dstar(const float* __restrict__ lib, const u32* __restrict__ scal,
                        u64* __restrict__ dstar) {
  int gid = blockIdx.x * 256 + threadIdx.x;
  int w = gid >> 6, lane = gid & 63;
  int quad = lane >> 4, l15 = lane & 15;
  u32 jstar = scal[1];
  const float4* ms = (const float4*)(lib + (size_t)jstar * DD);  // 96 float4
  float4 m[6];
#pragma unroll
  for (int j = 0; j < 6; ++j) m[j] = ms[j * 16 + l15];
  for (int r4 = w; r4 < 50000; r4 += 3200) {
    int row = r4 * 4 + quad;
    const float4* xr = (const float4*)(lib + (size_t)row * DD);
    float dot = 0.f;
#pragma unroll
    for (int j = 0; j < 6; ++j) {
      float4 x = xr[j * 16 + l15];
      dot += m[j].x * x.x + m[j].y * x.y + m[j].z * x.z + m[j].w * x.w;
    }
#pragma unroll
    for (int mm = 1; mm < 16; mm <<= 1) dot += __shfl_xor(dot, mm, 64);
    if (l15 == 0) {
      float dist = sqrtf(fmaxf(2.f - 2.f * dot, 0.f));
      dstar[row] = ((u64)__float_as_uint(dist) << 32) | (u32)row;
    }
  }
}

__device__ inline void merge5(const u64* a, const u64* b, u64* o) {
  int ia = 0, ib = 0;
#pragma unroll
  for (int j = 0; j < 5; ++j) {
    u64 va = a[ia], vb = b[ib];
    if (va <= vb) { o[j] = va; ++ia; } else { o[j] = vb; ++ib; }
  }
}

// ---- K5a: per-block top-5 smallest of d_star ----
__global__ void k_top5a(const u64* __restrict__ dstar, u64* __restrict__ tops) {
  __shared__ u64 l[256 * 5];
  int t = threadIdx.x, b = blockIdx.x;
  int start = b * 1563;
  int end = start + 1563; if (end > MM) end = MM;
  u64 a0 = ~0ull, a1 = ~0ull, a2 = ~0ull, a3 = ~0ull, a4 = ~0ull;
  for (int i = start + t; i < end; i += 256) {
    u64 v = dstar[i];
    if (v < a4) {
      if (v < a0)      { a4 = a3; a3 = a2; a2 = a1; a1 = a0; a0 = v; }
      else if (v < a1) { a4 = a3; a3 = a2; a2 = a1; a1 = v; }
      else if (v < a2) { a4 = a3; a3 = a2; a2 = v; }
      else if (v < a3) { a4 = a3; a3 = v; }
      else             { a4 = v; }
    }
  }
  l[t * 5 + 0] = a0; l[t * 5 + 1] = a1; l[t * 5 + 2] = a2; l[t * 5 + 3] = a3; l[t * 5 + 4] = a4;
  __syncthreads();
  for (int s = 128; s > 0; s >>= 1) {
    if (t < s) {
      u64 o[5];
      merge5(&l[t * 5], &l[(t + s) * 5], o);
#pragma unroll
      for (int j = 0; j < 5; ++j) l[t * 5 + j] = o[j];
    }
    __syncthreads();
  }
  if (t < 5) tops[b * 5 + t] = l[t];
}

// ---- K5b: global top-5 merge + final scalar s ----
__global__ void k_final(const u64* __restrict__ tops, const u32* __restrict__ scal,
                        const float* __restrict__ pnorm, const float* __restrict__ lib,
                        float* __restrict__ out) {
  __shared__ u64 l[128 * 5];
  __shared__ u32 nn[5];
  int t = threadIdx.x;
  if (t < 128) {
#pragma unroll
    for (int j = 0; j < 5; ++j) l[t * 5 + j] = tops[t * 5 + j];
  }
  __syncthreads();
  for (int s = 64; s > 0; s >>= 1) {
    if (t < s) {
      u64 o[5];
      merge5(&l[t * 5], &l[(t + s) * 5], o);
#pragma unroll
      for (int j = 0; j < 5; ++j) l[t * 5 + j] = o[j];
    }
    __syncthreads();
  }
  if (t < 5) nn[t] = (u32)l[t];
  __syncthreads();
  if (t < 64) {
    int lane = t;
    u32 sidx = scal[0], jstar = scal[1];
    const float* mt = pnorm + (size_t)sidx * DD;
    float mtv[6];
#pragma unroll
    for (int r = 0; r < 6; ++r) mtv[r] = mt[lane + 64 * r];
    float dist[6];
    for (int n = 0; n < 6; ++n) {
      u32 idx = (n == 0) ? jstar : nn[n - 1];
      const float* v = lib + (size_t)idx * DD;
      float p = 0.f;
#pragma unroll
      for (int r = 0; r < 6; ++r) {
        float d = mtv[r] - v[lane + 64 * r];
        p += d * d;
      }
#pragma unroll
      for (int m = 1; m < 64; m <<= 1) p += __shfl_xor(p, m, 64);
      dist[n] = sqrtf(p);
    }
    if (lane == 0) {
      float nrm = dist[0];  // ||m_test_star - m_star|| == s_star (fp32)
      float den = 0.f;
      for (int n = 1; n < 6; ++n) den += expf(dist[n]);
      out[0] = (1.f - expf(nrm) / den) * nrm;
    }
  }
}

// ---- K6: bilinear resize 26x26 -> 224x224 (half-pixel, clamped) ----
__global__ void k_resize(const float* __restrict__ mv, float* __restrict__ A) {
  int i = blockIdx.x * 256 + threadIdx.x;
  int Y = i / IMG, X = i - Y * IMG;
  const float sc = 26.f / 224.f;
  float sy = (Y + 0.5f) * sc - 0.5f;
  float sx = (X + 0.5f) * sc - 0.5f;
  float fy = sy - floorf(sy), fx = sx - floorf(sx);
  int y0 = (int)floorf(sy), x0 = (int)floorf(sx);
  int y1 = y0 + 1, x1 = x0 + 1;
  y0 = min(max(y0, 0), 25); y1 = min(max(y1, 0), 25);
  x0 = min(max(x0, 0), 25); x1 = min(max(x1, 0), 25);
  float v00 = mv[y0 * 26 + x0], v01 = mv[y0 * 26 + x1];
  float v10 = mv[y1 * 26 + x0], v11 = mv[y1 * 26 + x1];
  A[i] = (1.f - fy) * ((1.f - fx) * v00 + fx * v01) + fy * ((1.f - fx) * v10 + fx * v11);
}

// ---- K7/K8: separable 33-tap Gaussian (sigma=4), reflect padding ----
__global__ void k_blurh(const float* __restrict__ A, float* __restrict__ B) {
  __shared__ float kw[33];
  __shared__ float kinv;
  int t = threadIdx.x;
  if (t < 33) {
    float x = ((float)t - 16.f) * 0.25f;
    kw[t] = expf(-0.5f * x * x);
  }
  __syncthreads();
  if (t == 0) {
    float s = 0.f;
    for (int j = 0; j < 33; ++j) s += kw[j];
    kinv = 1.f / s;
  }
  __syncthreads();
  int i = blockIdx.x * 256 + t;
  int Y = i / IMG, X = i - Y * IMG;
  float s = 0.f;
  for (int j = 0; j < 33; ++j) {
    int xx = X + j - 16;
    xx = xx < 0 ? -xx : (xx > 223 ? 446 - xx : xx);
    s += kw[j] * A[Y * IMG + xx];
  }
  B[i] = s * kinv;
}

__global__ void k_blurv(const float* __restrict__ B, float* __restrict__ out) {
  __shared__ float kw[33];
  __shared__ float kinv;
  int t = threadIdx.x;
  if (t < 33) {
    float x = ((float)t - 16.f) * 0.25f;
    kw[t] = expf(-0.5f * x * x);
  }
  __syncthreads();
  if (t == 0) {
    float s = 0.f;
    for (int j = 0; j < 33; ++j) s += kw[j];
    kinv = 1.f / s;
  }
  __syncthreads();
  int i = blockIdx.x * 256 + t;
  int Y = i / IMG, X = i - Y * IMG;
  float s = 0.f;
  for (int j = 0; j < 33; ++j) {
    int yy = Y + j - 16;
    yy = yy < 0 ? -yy : (yy > 223 ? 446 - yy : yy);
    s += kw[j] * B[yy * IMG + X];
  }
  out[1 + i] = s * kinv;  // out[0] = s scalar, map follows
}

extern "C" void kernel_launch(void* const* d_in, const int* in_sizes, int n_in,
                              void* d_out, int out_size, void* d_ws, size_t ws_size,
                              hipStream_t stream) {
  const float* patch = (const float*)d_in[0];   // [676, 384]
  const float* lib   = (const float*)d_in[1];   // [200000, 384]
  float* out = (float*)d_out;                   // [1 + 224*224]
  char* w = (char*)d_ws;

  u64*  packed_ = (u64*)(w + WS_PACKED);
  u32*  scal    = (u32*)(w + WS_SCAL);
  float* mv     = (float*)(w + WS_MV);
  u64*  tops    = (u64*)(w + WS_TOPS);
  float* pnorm  = (float*)(w + WS_PNORM);
  unsigned short* pnb = (unsigned short*)(w + WS_PNB);
  u64*  dstar   = (u64*)(w + WS_DSTAR);
  float* bufA   = (float*)(w + WS_BUFA);
  float* bufB   = (float*)(w + WS_BUFB);

  k_init  <<<3,   256, 0, stream>>>(packed_);
  k_norm  <<<NPAD,128, 0, stream>>>(patch, pnorm, pnb);
  k_pass1 <<<782, 256, 0, stream>>>(pnb, lib, packed_);
  k_select<<<1,   256, 0, stream>>>(packed_, scal, mv);
  k_dstar <<<800, 256, 0, stream>>>(lib, scal, dstar);
  k_top5a <<<128, 256, 0, stream>>>(dstar, tops);
  k_final <<<1,   256, 0, stream>>>(tops, scal, pnorm, lib, out);
  k_resize<<<196, 256, 0, stream>>>(mv, bufA);
  k_blurh <<<196, 256, 0, stream>>>(bufA, bufB);
  k_blurv <<<196, 256, 0, stream>>>(bufB, out);
}

// Round 3
// 788.592 us; speedup vs baseline: 1.4686x; 1.3883x over previous
//
#include <hip/hip_runtime.h>
#include <stdint.h>

#define NP    676
#define NPAD  768
#define DD    384
#define MM    200000
#define IMG   224

typedef unsigned int u32;
typedef unsigned long long u64;
typedef short bf16x8 __attribute__((ext_vector_type(8)));
typedef float f32x4 __attribute__((ext_vector_type(4)));

// ---- workspace layout (bytes) ----
#define WS_PACKED   0u         // u64[768]   max-dot keys per row
#define WS_SCAL     6144u      // u32 s_idx, u32 j_star, f32 s_star
#define WS_MV       6400u      // f32[768]   min_val per row
#define WS_TOPS     9728u      // u64[128*5] per-block top5 of d_star
#define WS_PNORM    15360u     // f32[768*384] normalized patch
#define WS_PNB      1195008u   // ushort[768*384] bf16 normalized patch
#define WS_DSTAR    1784832u   // u64[200000] packed (dist,idx)
#define WS_BUFA     3384832u   // f32[50176] resized map
#define WS_BUFB     3585536u   // f32[50176] h-blurred map
#define WS_LIBH     3786240u   // ushort[200000*384] bf16 lib (153.6 MB)

__device__ inline unsigned short f2bf(float f) {
  u32 u = __float_as_uint(f);
  u += 0x7FFFu + ((u >> 16) & 1u);
  return (unsigned short)(u >> 16);
}
__device__ inline float bflo(u32 u) { return __uint_as_float(u << 16); }
__device__ inline float bfhi(u32 u) { return __uint_as_float(u & 0xFFFF0000u); }
// monotonic u32 key for float (ascending float -> ascending key)
__device__ inline u32 flipf(float f) {
  u32 u = __float_as_uint(f);
  return u ^ ((u32)((int)u >> 31) | 0x80000000u);
}
__device__ inline float unflipf(u32 k) {
  u32 u = (k & 0x80000000u) ? (k ^ 0x80000000u) : ~k;
  return __uint_as_float(u);
}

// ---- K0: init packed keys to 0 (all real keys > 0) ----
__global__ void k_init(u64* __restrict__ packed_) {
  int i = blockIdx.x * 256 + threadIdx.x;
  if (i < NPAD) packed_[i] = 0ull;
}

// ---- K1: L2-normalize patch rows, write fp32 + bf16, pad rows to 768 ----
__global__ void k_norm(const float* __restrict__ patch, float* __restrict__ pnorm,
                       unsigned short* __restrict__ pnb) {
  __shared__ float red[2];
  __shared__ float scs;
  int i = blockIdx.x, t = threadIdx.x;
  if (i >= NP) {
    for (int j = 0; j < 3; ++j) {
      pnorm[(size_t)i * DD + t + 128 * j] = 0.f;
      pnb[(size_t)i * DD + t + 128 * j] = 0;
    }
    return;
  }
  float x0 = patch[(size_t)i * DD + t];
  float x1 = patch[(size_t)i * DD + t + 128];
  float x2 = patch[(size_t)i * DD + t + 256];
  float s = x0 * x0 + x1 * x1 + x2 * x2;
#pragma unroll
  for (int m = 1; m < 64; m <<= 1) s += __shfl_xor(s, m, 64);
  if ((t & 63) == 0) red[t >> 6] = s;
  __syncthreads();
  if (t == 0) scs = 1.f / fmaxf(sqrtf(red[0] + red[1]), 1e-12f);
  __syncthreads();
  float k = scs;
  pnorm[(size_t)i * DD + t]       = x0 * k;
  pnorm[(size_t)i * DD + t + 128] = x1 * k;
  pnorm[(size_t)i * DD + t + 256] = x2 * k;
  pnb[(size_t)i * DD + t]       = f2bf(x0 * k);
  pnb[(size_t)i * DD + t + 128] = f2bf(x1 * k);
  pnb[(size_t)i * DD + t + 256] = f2bf(x2 * k);
}

// ---- K1b: one-time lib fp32 -> bf16 (bf16 lib fits in L3) ----
__global__ void k_conv(const float* __restrict__ lib, unsigned short* __restrict__ libh) {
  const size_t n4 = (size_t)MM * DD / 8;   // output uint4 units (8 bf16)
  const size_t stride = (size_t)gridDim.x * 256;
  const float4* src = (const float4*)lib;
  uint4* dst = (uint4*)libh;
  for (size_t i = (size_t)blockIdx.x * 256 + threadIdx.x; i < n4; i += stride) {
    float4 f0 = src[2 * i], f1 = src[2 * i + 1];
    uint4 o;
    o.x = (u32)f2bf(f0.x) | ((u32)f2bf(f0.y) << 16);
    o.y = (u32)f2bf(f0.z) | ((u32)f2bf(f0.w) << 16);
    o.z = (u32)f2bf(f1.x) | ((u32)f2bf(f1.y) << 16);
    o.w = (u32)f2bf(f1.z) | ((u32)f2bf(f1.w) << 16);
    dst[i] = o;
  }
}

// ---- K2: main pass. Grid = 782 col-chunks x 3 row-groups (rg minor -> L3 shares B).
// Wave owns 64 rows; A fragments register-resident for full K (192 VGPRs).
// B streamed as 32-col double-buffered LDS chunks; 4 MFMA per B-frag ds_read.
__global__ __launch_bounds__(256, 2) void k_pass1(const unsigned short* __restrict__ pnb,
                                                  const unsigned short* __restrict__ libh,
                                                  u64* __restrict__ packed_) {
  __shared__ __align__(16) unsigned short bt[2][32 * 392];   // 2 x 25088 B
  const int t = threadIdx.x;
  const int b = blockIdx.x;
  const int cc = b / 3, rg = b - cc * 3;
  const int col0 = cc * 256;
  const int rowbase = rg * 256;
  const int wave = t >> 6, lane = t & 63;
  const int quad = lane >> 4, l15 = lane & 15;
  const int nchunk = (MM - col0 < 256) ? (MM - col0) / 32 : 8;

  // ---- prologue: A fragments -> registers via LDS bounce (8 pieces of 32 rows)
  bf16x8 areg[4][12];
#pragma unroll
  for (int p = 0; p < 8; ++p) {
    __syncthreads();
    {
      const uint4* src = (const uint4*)(pnb + (size_t)(rowbase + p * 32) * DD);
#pragma unroll
      for (int it = 0; it < 6; ++it) {
        int u = it * 256 + t;
        int r = u / 48, k16 = u - r * 48;
        *(uint4*)&bt[0][r * 392 + k16 * 8] = src[u];
      }
    }
    __syncthreads();
    if ((p >> 1) == wave) {
#pragma unroll
      for (int j = 0; j < 2; ++j) {
        const int mi = (p & 1) * 2 + j;
        const unsigned short* ap = &bt[0][(j * 16 + l15) * 392 + quad * 8];
#pragma unroll
        for (int kt = 0; kt < 12; ++kt)
          areg[mi][kt] = *(const bf16x8*)(ap + kt * 32);
      }
    }
  }
  __syncthreads();   // all frag reads done before chunk-0 staging reuses bt[0]

  u32 best[16];
#pragma unroll
  for (int j = 0; j < 16; ++j) best[j] = 0u;

  // prefetch chunk 0 into buf 0
  {
    const uint4* src = (const uint4*)(libh + (size_t)col0 * DD);
#pragma unroll
    for (int it = 0; it < 6; ++it) {
      int u = it * 256 + t;
      int r = u / 48, k16 = u - r * 48;
      *(uint4*)&bt[0][r * 392 + k16 * 8] = src[u];
    }
  }
  __syncthreads();

#pragma unroll 1
  for (int c = 0; c < nchunk; ++c) {
    const int buf = c & 1;
    const bool more = (c + 1 < nchunk);
    const uint4* src = (const uint4*)(libh + (size_t)(col0 + (c + 1) * 32) * DD);
    uint4 pre[3];
    if (more) {
#pragma unroll
      for (int it = 0; it < 3; ++it) pre[it] = src[it * 256 + t];
    }
#pragma unroll
    for (int ncb = 0; ncb < 2; ++ncb) {
      f32x4 acc[4];
#pragma unroll
      for (int mi = 0; mi < 4; ++mi) {
        acc[mi][0] = 0.f; acc[mi][1] = 0.f; acc[mi][2] = 0.f; acc[mi][3] = 0.f;
      }
      const unsigned short* bp = &bt[buf][(ncb * 16 + l15) * 392 + quad * 8];
#pragma unroll
      for (int kt = 0; kt < 12; ++kt) {
        bf16x8 bf = *(const bf16x8*)(bp + kt * 32);
#pragma unroll
        for (int mi = 0; mi < 4; ++mi)
          acc[mi] = __builtin_amdgcn_mfma_f32_16x16x32_bf16(areg[mi][kt], bf, acc[mi], 0, 0, 0);
      }
      // fold: key = dot[31:8] | (255 - col_in_wg)  (smaller col wins ties)
      const u32 colbits = 255u - (u32)(c * 32 + ncb * 16 + l15);
#pragma unroll
      for (int mi = 0; mi < 4; ++mi)
#pragma unroll
        for (int r = 0; r < 4; ++r) {
          u32 k = (flipf(acc[mi][r]) & 0xFFFFFF00u) | colbits;
          if (k > best[mi * 4 + r]) best[mi * 4 + r] = k;
        }
      // interleaved staging: write first half after ncb0, load+write second half
      if (more) {
        if (ncb == 0) {
#pragma unroll
          for (int it = 0; it < 3; ++it) {
            int u = it * 256 + t;
            int r = u / 48, k16 = u - r * 48;
            *(uint4*)&bt[buf ^ 1][r * 392 + k16 * 8] = pre[it];
          }
#pragma unroll
          for (int it = 0; it < 3; ++it) pre[it] = src[(it + 3) * 256 + t];
        } else {
#pragma unroll
          for (int it = 0; it < 3; ++it) {
            int u = (it + 3) * 256 + t;
            int r = u / 48, k16 = u - r * 48;
            *(uint4*)&bt[buf ^ 1][r * 392 + k16 * 8] = pre[it];
          }
        }
      }
    }
    __syncthreads();
  }

  // ---- epilogue: butterfly over the 16 col-lanes, then one global atomic/row
#pragma unroll
  for (int mi = 0; mi < 4; ++mi)
#pragma unroll
    for (int r = 0; r < 4; ++r) {
      u32 k = best[mi * 4 + r];
#pragma unroll
      for (int m = 1; m < 16; m <<= 1) {
        u32 o = (u32)__shfl_xor((int)k, m, 64);
        k = o > k ? o : k;
      }
      if (l15 == 0) {
        int col = col0 + 255 - (int)(k & 255u);
        int row = rowbase + wave * 64 + mi * 16 + quad * 4 + r;
        u64 g = ((u64)(k & 0xFFFFFF00u) << 32) | (u64)(0xFFFFFFFFu - (u32)col);
        atomicMax(&packed_[row], g);
      }
    }
}

// ---- K3: min_val[i], s_idx = argmax(min_val) (first-index tie), j_star ----
__global__ void k_select(const u64* __restrict__ packed_, u32* __restrict__ scal,
                         float* __restrict__ mv) {
  __shared__ u64 red[256];
  int t = threadIdx.x;
  u64 best = 0ull;
  for (int i = t; i < NP; i += 256) {
    u64 p = packed_[i];
    float d = unflipf((u32)(p >> 32));
    float dist = sqrtf(fmaxf(2.f - 2.f * d, 0.f));
    mv[i] = dist;
    u64 key = ((u64)__float_as_uint(dist) << 32) | (u32)(0xFFFFFFFFu - (u32)i);
    if (key > best) best = key;
  }
  red[t] = best;
  __syncthreads();
  for (int s = 128; s > 0; s >>= 1) {
    if (t < s && red[t + s] > red[t]) red[t] = red[t + s];
    __syncthreads();
  }
  if (t == 0) {
    u64 k = red[0];
    u32 sidx = 0xFFFFFFFFu - (u32)k;
    u64 p = packed_[sidx];
    u32 jstar = 0xFFFFFFFFu - (u32)p;
    scal[0] = sidx;
    scal[1] = jstar;
    ((float*)scal)[2] = __uint_as_float((u32)(k >> 32));
  }
}

// ---- K4: d_star from bf16 lib (selection only); 4 rows/wave via 16-lane groups
__global__ void k_dstar(const unsigned short* __restrict__ libh, const u32* __restrict__ scal,
                        u64* __restrict__ dstar) {
  int gid = blockIdx.x * 256 + threadIdx.x;
  int w = gid >> 6, lane = gid & 63;
  int quad = lane >> 4, l15 = lane & 15;
  u32 jstar = scal[1];
  const uint4* ms = (const uint4*)(libh + (size_t)jstar * DD);   // 48 uint4/row
  float mf[24];
#pragma unroll
  for (int j = 0; j < 3; ++j) {
    uint4 u = ms[j * 16 + l15];
    mf[j * 8 + 0] = bflo(u.x); mf[j * 8 + 1] = bfhi(u.x);
    mf[j * 8 + 2] = bflo(u.y); mf[j * 8 + 3] = bfhi(u.y);
    mf[j * 8 + 4] = bflo(u.z); mf[j * 8 + 5] = bfhi(u.z);
    mf[j * 8 + 6] = bflo(u.w); mf[j * 8 + 7] = bfhi(u.w);
  }
  for (int r4 = w; r4 < 50000; r4 += 3200) {
    int row = r4 * 4 + quad;
    const uint4* xr = (const uint4*)(libh + (size_t)row * DD);
    float dot = 0.f;
#pragma unroll
    for (int j = 0; j < 3; ++j) {
      uint4 u = xr[j * 16 + l15];
      dot += mf[j * 8 + 0] * bflo(u.x) + mf[j * 8 + 1] * bfhi(u.x);
      dot += mf[j * 8 + 2] * bflo(u.y) + mf[j * 8 + 3] * bfhi(u.y);
      dot += mf[j * 8 + 4] * bflo(u.z) + mf[j * 8 + 5] * bfhi(u.z);
      dot += mf[j * 8 + 6] * bflo(u.w) + mf[j * 8 + 7] * bfhi(u.w);
    }
#pragma unroll
    for (int mm = 1; mm < 16; mm <<= 1) dot += __shfl_xor(dot, mm, 64);
    if (l15 == 0) {
      float dist = sqrtf(fmaxf(2.f - 2.f * dot, 0.f));
      dstar[row] = ((u64)__float_as_uint(dist) << 32) | (u32)row;
    }
  }
}

__device__ inline void merge5(const u64* a, const u64* b, u64* o) {
  int ia = 0, ib = 0;
#pragma unroll
  for (int j = 0; j < 5; ++j) {
    u64 va = a[ia], vb = b[ib];
    if (va <= vb) { o[j] = va; ++ia; } else { o[j] = vb; ++ib; }
  }
}

// ---- K5a: per-block top-5 smallest of d_star ----
__global__ void k_top5a(const u64* __restrict__ dstar, u64* __restrict__ tops) {
  __shared__ u64 l[256 * 5];
  int t = threadIdx.x, b = blockIdx.x;
  int start = b * 1563;
  int end = start + 1563; if (end > MM) end = MM;
  u64 a0 = ~0ull, a1 = ~0ull, a2 = ~0ull, a3 = ~0ull, a4 = ~0ull;
  for (int i = start + t; i < end; i += 256) {
    u64 v = dstar[i];
    if (v < a4) {
      if (v < a0)      { a4 = a3; a3 = a2; a2 = a1; a1 = a0; a0 = v; }
      else if (v < a1) { a4 = a3; a3 = a2; a2 = a1; a1 = v; }
      else if (v < a2) { a4 = a3; a3 = a2; a2 = v; }
      else if (v < a3) { a4 = a3; a3 = v; }
      else             { a4 = v; }
    }
  }
  l[t * 5 + 0] = a0; l[t * 5 + 1] = a1; l[t * 5 + 2] = a2; l[t * 5 + 3] = a3; l[t * 5 + 4] = a4;
  __syncthreads();
  for (int s = 128; s > 0; s >>= 1) {
    if (t < s) {
      u64 o[5];
      merge5(&l[t * 5], &l[(t + s) * 5], o);
#pragma unroll
      for (int j = 0; j < 5; ++j) l[t * 5 + j] = o[j];
    }
    __syncthreads();
  }
  if (t < 5) tops[b * 5 + t] = l[t];
}

// ---- K5b: global top-5 merge + final scalar s (exact fp32 via lib/pnorm) ----
__global__ void k_final(const u64* __restrict__ tops, const u32* __restrict__ scal,
                        const float* __restrict__ pnorm, const float* __restrict__ lib,
                        float* __restrict__ out) {
  __shared__ u64 l[128 * 5];
  __shared__ u32 nn[5];
  int t = threadIdx.x;
  if (t < 128) {
#pragma unroll
    for (int j = 0; j < 5; ++j) l[t * 5 + j] = tops[t * 5 + j];
  }
  __syncthreads();
  for (int s = 64; s > 0; s >>= 1) {
    if (t < s) {
      u64 o[5];
      merge5(&l[t * 5], &l[(t + s) * 5], o);
#pragma unroll
      for (int j = 0; j < 5; ++j) l[t * 5 + j] = o[j];
    }
    __syncthreads();
  }
  if (t < 5) nn[t] = (u32)l[t];
  __syncthreads();
  if (t < 64) {
    int lane = t;
    u32 sidx = scal[0], jstar = scal[1];
    const float* mt = pnorm + (size_t)sidx * DD;
    float mtv[6];
#pragma unroll
    for (int r = 0; r < 6; ++r) mtv[r] = mt[lane + 64 * r];
    float dist[6];
    for (int n = 0; n < 6; ++n) {
      u32 idx = (n == 0) ? jstar : nn[n - 1];
      const float* v = lib + (size_t)idx * DD;
      float p = 0.f;
#pragma unroll
      for (int r = 0; r < 6; ++r) {
        float d = mtv[r] - v[lane + 64 * r];
        p += d * d;
      }
#pragma unroll
      for (int m = 1; m < 64; m <<= 1) p += __shfl_xor(p, m, 64);
      dist[n] = sqrtf(p);
    }
    if (lane == 0) {
      float nrm = dist[0];  // ||m_test_star - m_star|| == s_star (fp32)
      float den = 0.f;
      for (int n = 1; n < 6; ++n) den += expf(dist[n]);
      out[0] = (1.f - expf(nrm) / den) * nrm;
    }
  }
}

// ---- K6: bilinear resize 26x26 -> 224x224 (half-pixel, clamped) ----
__global__ void k_resize(const float* __restrict__ mv, float* __restrict__ A) {
  int i = blockIdx.x * 256 + threadIdx.x;
  int Y = i / IMG, X = i - Y * IMG;
  const float sc = 26.f / 224.f;
  float sy = (Y + 0.5f) * sc - 0.5f;
  float sx = (X + 0.5f) * sc - 0.5f;
  float fy = sy - floorf(sy), fx = sx - floorf(sx);
  int y0 = (int)floorf(sy), x0 = (int)floorf(sx);
  int y1 = y0 + 1, x1 = x0 + 1;
  y0 = min(max(y0, 0), 25); y1 = min(max(y1, 0), 25);
  x0 = min(max(x0, 0), 25); x1 = min(max(x1, 0), 25);
  float v00 = mv[y0 * 26 + x0], v01 = mv[y0 * 26 + x1];
  float v10 = mv[y1 * 26 + x0], v11 = mv[y1 * 26 + x1];
  A[i] = (1.f - fy) * ((1.f - fx) * v00 + fx * v01) + fy * ((1.f - fx) * v10 + fx * v11);
}

// ---- K7/K8: separable 33-tap Gaussian (sigma=4), reflect padding ----
__global__ void k_blurh(const float* __restrict__ A, float* __restrict__ B) {
  __shared__ float kw[33];
  __shared__ float kinv;
  int t = threadIdx.x;
  if (t < 33) {
    float x = ((float)t - 16.f) * 0.25f;
    kw[t] = expf(-0.5f * x * x);
  }
  __syncthreads();
  if (t == 0) {
    float s = 0.f;
    for (int j = 0; j < 33; ++j) s += kw[j];
    kinv = 1.f / s;
  }
  __syncthreads();
  int i = blockIdx.x * 256 + t;
  int Y = i / IMG, X = i - Y * IMG;
  float s = 0.f;
  for (int j = 0; j < 33; ++j) {
    int xx = X + j - 16;
    xx = xx < 0 ? -xx : (xx > 223 ? 446 - xx : xx);
    s += kw[j] * A[Y * IMG + xx];
  }
  B[i] = s * kinv;
}

__global__ void k_blurv(const float* __restrict__ B, float* __restrict__ out) {
  __shared__ float kw[33];
  __shared__ float kinv;
  int t = threadIdx.x;
  if (t < 33) {
    float x = ((float)t - 16.f) * 0.25f;
    kw[t] = expf(-0.5f * x * x);
  }
  __syncthreads();
  if (t == 0) {
    float s = 0.f;
    for (int j = 0; j < 33; ++j) s += kw[j];
    kinv = 1.f / s;
  }
  __syncthreads();
  int i = blockIdx.x * 256 + t;
  int Y = i / IMG, X = i - Y * IMG;
  float s = 0.f;
  for (int j = 0; j < 33; ++j) {
    int yy = Y + j - 16;
    yy = yy < 0 ? -yy : (yy > 223 ? 446 - yy : yy);
    s += kw[j] * B[yy * IMG + X];
  }
  out[1 + i] = s * kinv;  // out[0] = s scalar, map follows
}

extern "C" void kernel_launch(void* const* d_in, const int* in_sizes, int n_in,
                              void* d_out, int out_size, void* d_ws, size_t ws_size,
                              hipStream_t stream) {
  const float* patch = (const float*)d_in[0];   // [676, 384]
  const float* lib   = (const float*)d_in[1];   // [200000, 384]
  float* out = (float*)d_out;                   // [1 + 224*224]
  char* w = (char*)d_ws;

  u64*  packed_ = (u64*)(w + WS_PACKED);
  u32*  scal    = (u32*)(w + WS_SCAL);
  float* mv     = (float*)(w + WS_MV);
  u64*  tops    = (u64*)(w + WS_TOPS);
  float* pnorm  = (float*)(w + WS_PNORM);
  unsigned short* pnb  = (unsigned short*)(w + WS_PNB);
  u64*  dstar   = (u64*)(w + WS_DSTAR);
  float* bufA   = (float*)(w + WS_BUFA);
  float* bufB   = (float*)(w + WS_BUFB);
  unsigned short* libh = (unsigned short*)(w + WS_LIBH);

  k_init  <<<3,    256, 0, stream>>>(packed_);
  k_norm  <<<NPAD, 128, 0, stream>>>(patch, pnorm, pnb);
  k_conv  <<<2048, 256, 0, stream>>>(lib, libh);
  k_pass1 <<<2346, 256, 0, stream>>>(pnb, libh, packed_);
  k_select<<<1,    256, 0, stream>>>(packed_, scal, mv);
  k_dstar <<<800,  256, 0, stream>>>(libh, scal, dstar);
  k_top5a <<<128,  256, 0, stream>>>(dstar, tops);
  k_final <<<1,    256, 0, stream>>>(tops, scal, pnorm, lib, out);
  k_resize<<<196,  256, 0, stream>>>(mv, bufA);
  k_blurh <<<196,  256, 0, stream>>>(bufA, bufB);
  k_blurv <<<196,  256, 0, stream>>>(bufB, out);
}